// Round 12
// baseline (150.468 us; speedup 1.0000x reference)
//
#include <hip/hip_runtime.h>

// ---------------- problem constants ----------------
constexpr int Bc = 2, Nc = 256, CHM = 62;
constexpr int HW = 180;            // heatmap H=W
constexpr int OH = 38;             // conv out H=W
constexpr int Pp = OH * OH;        // 1444 positions
constexpr int NIMG = Bc * Nc;      // 512 images (n-major: img = n*B + b)
constexpr int R2 = 8;              // output rows per conv block
constexpr int NRB2 = 5;            // row-blocks per image (8,8,8,8,6)
constexpr int NBLK2 = NIMG * NRB2; // 2560
constexpr int KP = 576;            // padded K = 9 taps * 64 ch

// ---------------- ws layout (bytes) ----------------
constexpr size_t OFF_THETA = 0;            // 512*6*4        = 12,288
constexpr size_t OFF_WB    = 16384;        // 64*576*2 bf16  = 73,728
constexpr size_t OFF_AB    = 90112;        // 64*2*4         = 512
// hmT path:
constexpr size_t OFF_HMT    = 131072;      // 2*180*180*64*2 = 8,294,400 -> 8,425,472
constexpr size_t OFF_PART_H = 8425472;     // 2560*64*2*4    = 1,310,720 -> 9,736,192
constexpr size_t OFF_CONV_H = 9736192;     // + 94,633,984   -> 104,370,176
constexpr size_t NEED_HMT   = 104370176;   // proven available (rounds 4-11 ran this path)
// legacy path (no hmT):
constexpr size_t OFF_PART_L = 131072;
constexpr size_t OFF_CONV_L = 1441792;     // + 94,633,984 -> 96,075,776

typedef __attribute__((ext_vector_type(8))) short  short8;
typedef __attribute__((ext_vector_type(8))) __bf16 bf16x8;
typedef __attribute__((ext_vector_type(4))) float  f32x4;
typedef __attribute__((ext_vector_type(2))) float  f32x2;

__device__ __forceinline__ bf16x8 bc(short8 v) { return __builtin_bit_cast(bf16x8, v); }
__device__ __forceinline__ float tof(short s) {
    return __uint_as_float(((unsigned)(unsigned short)s) << 16);
}
__device__ __forceinline__ f32x2 up2(unsigned u) {
    f32x2 r;
    r.x = __uint_as_float(u << 16);
    r.y = __uint_as_float(u & 0xffff0000u);
    return r;
}

// ============ K1 (merged): theta MLP | weight cvt | heatmap transpose ============
// blocks [0,512): theta; [512,656): wcvt; [656,1016): hmT
__global__ __launch_bounds__(256) void k_prep(
    const float* __restrict__ q,
    const float* __restrict__ w1, const float* __restrict__ b1,
    const float* __restrict__ w2, const float* __restrict__ b2,
    const float* __restrict__ w3, const float* __restrict__ b3,
    const float* __restrict__ cw, const float* __restrict__ hm,
    float* __restrict__ theta, __bf16* __restrict__ wb, __bf16* __restrict__ hmT) {
    int bid = blockIdx.x, t = threadIdx.x;
    if (bid < 512) {
        __shared__ float qv[256], h1[64], h2[64];
        int qi = bid;              // = b*N + n
        int b = qi >> 8, n = qi & 255;
        qv[t] = q[qi * 256 + t];
        __syncthreads();
        if (t < 64) {
            float s = b1[t];
            const float* wr = w1 + t * 256;
            for (int i = 0; i < 256; ++i) s = fmaf(qv[i], wr[i], s);
            h1[t] = fmaxf(s, 0.f);
        }
        __syncthreads();
        if (t < 64) {
            float s = b2[t];
            const float* wr = w2 + t * 64;
            for (int i = 0; i < 64; ++i) s = fmaf(h1[i], wr[i], s);
            h2[t] = fmaxf(s, 0.f);
        }
        __syncthreads();
        if (t < 6) {
            float s = b3[t];
            const float* wr = w3 + t * 64;
            for (int i = 0; i < 64; ++i) s = fmaf(h2[i], wr[i], s);
            theta[(n * Bc + b) * 6 + t] = s;
        }
    } else if (bid < 656) {
        int idx = (bid - 512) * 256 + t;           // over 64*576 exactly
        int n = idx / KP, k = idx - n * KP;
        int tap = k >> 6, ic = k & 63;
        float v = (ic < CHM) ? cw[(n * CHM + ic) * 9 + tap] : 0.f;
        wb[idx] = (__bf16)v;
    } else {
        int by = bid - 656;                        // b*180 + y
        int b = by / HW, y = by - b * HW;
        int x = t;
        if (x < HW) {
            const float* src = hm + (size_t)b * CHM * (HW * HW) + y * HW + x;
            __bf16* dst = hmT + ((size_t)(b * (HW * HW) + y * HW + x)) * 64;
#pragma unroll
            for (int g = 0; g < 8; ++g) {
                bf16x8 v;
#pragma unroll
                for (int j = 0; j < 8; ++j) {
                    int c = g * 8 + j;
                    v[j] = (c < CHM) ? (__bf16)src[(size_t)c * (HW * HW)] : (__bf16)0.f;
                }
                *(bf16x8*)(dst + g * 8) = v;
            }
        }
    }
}

// ============ K3: fused sample + MFMA implicit-GEMM conv ============
// 512 threads = 8 waves = 2 oc-halves (hg, 32 oc each) x 4 row-pairs (qp).
// strip LDS: [rx<=10*40][ic:64] bf16, 16B-granular swizzle: elem ^= (x&7)<<3
// sampling (HMT): task = (position, 8ch-group); 8 consecutive lanes share one
// 128B corner vector (round-8 proven); f32x2 pk-fma blend.
// m-loop: s OUTER; one A ds_read feeds TWO MFMAs (2 n-tiles/wave) -> A-read
// LDS traffic halved vs round 11 (was 74% of the CU LDS port).
#define PREP(S, PIDX, VLD) \
    int o00##S, o10##S, o01##S, o11##S, eb##S, sw##S; \
    float w00##S, w10##S, w01##S, w11##S; \
    { int _p = (PIDX); \
      int _r = _p / 40, _x = _p - _r * 40; \
      float _gx = (2 * _x + 1) * 0.025f - 1.f; \
      float _gy = (2 * (oy0 + _r) + 1) * 0.025f - 1.f; \
      float _X = fmaf(t00, _gx, fmaf(t01, _gy, t02)); \
      float _Y = fmaf(t10, _gx, fmaf(t11, _gy, t12)); \
      float _ix = fmaf(_X, 90.f, 89.5f), _iy = fmaf(_Y, 90.f, 89.5f); \
      float _xf = floorf(_ix), _yf = floorf(_iy); \
      float _fx = _ix - _xf, _fy = _iy - _yf; \
      int _x0 = (int)_xf, _y0 = (int)_yf; \
      bool _xi0 = (unsigned)_x0 < (unsigned)HW, _xi1 = (unsigned)(_x0 + 1) < (unsigned)HW; \
      bool _yi0 = (unsigned)_y0 < (unsigned)HW, _yi1 = (unsigned)(_y0 + 1) < (unsigned)HW; \
      float _vm = (VLD) ? 1.f : 0.f; \
      w00##S = (_xi0 & _yi0) ? (1.f - _fx) * (1.f - _fy) * _vm : 0.f; \
      w10##S = (_xi1 & _yi0) ? _fx * (1.f - _fy) * _vm : 0.f; \
      w01##S = (_xi0 & _yi1) ? (1.f - _fx) * _fy * _vm : 0.f; \
      w11##S = (_xi1 & _yi1) ? _fx * _fy * _vm : 0.f; \
      o00##S = (_xi0 & _yi0) ? _y0 * HW + _x0 : 0; \
      o10##S = (_xi1 & _yi0) ? _y0 * HW + _x0 + 1 : 0; \
      o01##S = (_xi0 & _yi1) ? (_y0 + 1) * HW + _x0 : 0; \
      o11##S = (_xi1 & _yi1) ? (_y0 + 1) * HW + _x0 + 1 : 0; \
      eb##S = _p << 6; sw##S = (_x & 7) << 3; \
    }

template<int HMT>
__global__ __launch_bounds__(512, 4) void k_conv2(
    const float* __restrict__ heatmap, const __bf16* __restrict__ hmT,
    const float* __restrict__ theta, const __bf16* __restrict__ wb,
    const float* __restrict__ bias, float* __restrict__ partials,
    __bf16* __restrict__ conv_out) {
    __shared__ char smem[53248];                 // 51200 strip + 2KB red

    int bid = blockIdx.x;
    int n = bid & 255, bsel = (bid >> 8) & 1, ry = bid >> 9;
    int img = n * Bc + bsel;
    int oy0 = ry * R2;
    int nr  = (ry == NRB2 - 1) ? 6 : 8;          // output rows this block
    int t = threadIdx.x;
    int lane = t & 63, wv = t >> 6;
    int col = lane & 15, chunk = lane >> 4;
    int hg = wv & 1, qp = wv >> 1;               // oc-half, row-pair

    // ---- sampling ----
    const float* th = theta + img * 6;
    float t00 = th[0], t01 = th[1], t02 = th[2];
    float t10 = th[3], t11 = th[4], t12 = th[5];
    int rows = nr + 2, npos = rows * 40;

    if constexpr (HMT) {
        const char* hb = (const char*)(hmT + (size_t)bsel * ((size_t)HW * HW * 64));
        int ntask = npos * 8;                    // (position, ch-group) tasks
        for (int v = t; v < ntask; v += 512) {
            int p = v >> 3, cg = v & 7;
            PREP(T, p, true)
            int co = cg * 16;                    // byte offset of 8-ch group
            uint4 d00 = *(const uint4*)(hb + (size_t)o00T * 128 + co);
            uint4 d10 = *(const uint4*)(hb + (size_t)o10T * 128 + co);
            uint4 d01 = *(const uint4*)(hb + (size_t)o01T * 128 + co);
            uint4 d11 = *(const uint4*)(hb + (size_t)o11T * 128 + co);
            f32x2 W00 = {w00T, w00T}, W10 = {w10T, w10T};
            f32x2 W01 = {w01T, w01T}, W11 = {w11T, w11T};
            bf16x8 v0;
#pragma unroll
            for (int j = 0; j < 4; ++j) {
                f32x2 r = up2((&d11.x)[j]) * W11;
                r = __builtin_elementwise_fma(up2((&d01.x)[j]), W01, r);
                r = __builtin_elementwise_fma(up2((&d10.x)[j]), W10, r);
                r = __builtin_elementwise_fma(up2((&d00.x)[j]), W00, r);
                v0[2 * j]     = (__bf16)r.x;
                v0[2 * j + 1] = (__bf16)r.y;
            }
            *(bf16x8*)(smem + 2 * (ebT | ((cg * 8) ^ swT))) = v0;
        }
    } else {
        if (t < npos) {
            PREP(A, t, true)
            char* sb0 = smem + 2 * ebA;
            const float* hmb = heatmap + (size_t)bsel * CHM * HW * HW;
            auto dofetch = [&](int c) -> float {
                const float* pl = hmb + c * (HW * HW);
                return fmaf(w00A, pl[o00A], fmaf(w10A, pl[o10A],
                       fmaf(w01A, pl[o01A], w11A * pl[o11A])));
            };
#pragma unroll
            for (int cg = 0; cg < 8; ++cg) {
                bf16x8 v0;
#pragma unroll
                for (int j = 0; j < 8; ++j) {
                    int c = cg * 8 + j;
                    v0[j] = (c < CHM) ? (__bf16)dofetch(c) : (__bf16)0.f;
                }
                *(bf16x8*)(sb0 + 2 * ((cg * 8) ^ swA)) = v0;
            }
        }
    }
    __syncthreads();

    // ---- MFMA m-loop: s OUTER; wave (hg,qp) -> 32 oc (2 n-tiles), 1 row-pair ----
    // lane m=col -> (x = xb*8 + (col&7), row = oyp + (col>>3)).
    float bia0 = bias[hg * 32 + col], bia1 = bias[hg * 32 + 16 + col];
    float ssum0 = 0.f, ssq0 = 0.f, ssum1 = 0.f, ssq1 = 0.f;
    int cl = col & 7;
    int ch8 = (col >> 3) * 5120;
    int cb = chunk << 4;
    int oyp = qp * 2;
    bool valid = (oyp + 1) < nr;                 // qp=3 idle when nr=6
    const char* wp0 = (const char*)wb + (size_t)(hg * 32 + col) * (KP * 2) + chunk * 16;
    const char* wp1 = wp0 + 16 * (KP * 2);
    int base0 = oyp * 5120;

    f32x4 accP[5], accQ[5];
#pragma unroll
    for (int xb = 0; xb < 5; ++xb) {
        accP[xb] = f32x4{0.f, 0.f, 0.f, 0.f};
        accQ[xb] = f32x4{0.f, 0.f, 0.f, 0.f};
    }

    if (valid) {
        __builtin_amdgcn_s_setprio(1);
#pragma unroll
        for (int s = 0; s < 18; ++s) {
            const int tap = s >> 1;
            const int ky = tap / 3, kx = tap % 3;
            const int hb2 = (s & 1) << 6;
            short8 bs0 = *(const short8*)(wp0 + s * 64);    // L2-hot B fragments
            short8 bs1 = *(const short8*)(wp1 + s * 64);
            int t1 = cl + kx;
            int loff = ch8 + ky * 5120 + t1 * 128 + ((hb2 | cb) ^ ((t1 & 7) << 4));
            const char* p0 = smem + base0 + loff;
#pragma unroll
            for (int xb = 0; xb < 5; ++xb) {
                short8 a0 = *(const short8*)(p0 + xb * 1024);
                accP[xb] = __builtin_amdgcn_mfma_f32_16x16x32_bf16(bc(a0), bc(bs0), accP[xb], 0, 0, 0);
                accQ[xb] = __builtin_amdgcn_mfma_f32_16x16x32_bf16(bc(a0), bc(bs1), accQ[xb], 0, 0, 0);
            }
        }
        __builtin_amdgcn_s_setprio(0);

        // epilogue: C row m = chunk*4+r2 -> x = xb*8 + (m&7), row = oyp + (m>>3)
        __bf16* cobase0 = conv_out + ((size_t)img * Pp + oy0 * 38) * 64 + (hg * 32 + col);
        __bf16* cobase1 = cobase0 + 16;
#pragma unroll
        for (int xb = 0; xb < 5; ++xb) {
#pragma unroll
            for (int r2 = 0; r2 < 4; ++r2) {
                int m = chunk * 4 + r2;
                int x = xb * 8 + (m & 7);
                if (x < 38) {
                    int row = oyp + (m >> 3);
                    size_t po = (size_t)(row * 38 + x) * 64;
                    float v0 = accP[xb][r2] + bia0;
                    cobase0[po] = (__bf16)v0;
                    ssum0 += v0; ssq0 = fmaf(v0, v0, ssq0);
                    float v1 = accQ[xb][r2] + bia1;
                    cobase1[po] = (__bf16)v1;
                    ssum1 += v1; ssq1 = fmaf(v1, v1, ssq1);
                }
            }
        }
    }

    // cross-lane: sum lanes {l, l^16, l^32, l^48} (same oc col)
    ssum0 += __shfl_xor(ssum0, 16); ssum0 += __shfl_xor(ssum0, 32);
    ssq0  += __shfl_xor(ssq0, 16);  ssq0  += __shfl_xor(ssq0, 32);
    ssum1 += __shfl_xor(ssum1, 16); ssum1 += __shfl_xor(ssum1, 32);
    ssq1  += __shfl_xor(ssq1, 16);  ssq1  += __shfl_xor(ssq1, 32);

    // combine 4 qp-waves via LDS red region [4][64][2] @ 51200
    float* redq = (float*)(smem + 51200);
    if (lane < 16) {
        int o = (qp * 64 + hg * 32 + lane) * 2;
        redq[o]      = ssum0; redq[o + 1]  = ssq0;
        redq[o + 32] = ssum1; redq[o + 33] = ssq1;   // +16 oc -> +32 floats
    }
    __syncthreads();
    if (t < 64) {
        float S = 0.f, S2 = 0.f;
#pragma unroll
        for (int g = 0; g < 4; ++g) {
            S  += redq[(g * 64 + t) * 2];
            S2 += redq[(g * 64 + t) * 2 + 1];
        }
        partials[((size_t)bid * 64 + t) * 2]     = S;
        partials[((size_t)bid * 64 + t) * 2 + 1] = S2;
    }
}

// ============ K3b: reduce per-block sums -> BN a,b per channel ============
__global__ void k_stats(const float* __restrict__ partials, const float* __restrict__ gamma,
                        const float* __restrict__ beta, float* __restrict__ ab) {
    __shared__ float red[256][2];
    int oc = blockIdx.x, t = threadIdx.x;
    float S = 0.f, S2 = 0.f;
    for (int j = t; j < NBLK2; j += 256) {
        S  += partials[((size_t)j * 64 + oc) * 2];
        S2 += partials[((size_t)j * 64 + oc) * 2 + 1];
    }
    red[t][0] = S; red[t][1] = S2;
    __syncthreads();
    for (int off = 128; off >= 1; off >>= 1) {
        if (t < off) { red[t][0] += red[t + off][0]; red[t][1] += red[t + off][1]; }
        __syncthreads();
    }
    if (t == 0) {
        float cnt = (float)NIMG * (float)Pp;
        float mu  = red[0][0] / cnt;
        float var = red[0][1] / cnt - mu * mu;
        float a = gamma[oc] * rsqrtf(var + 1e-5f);
        ab[oc * 2] = a;
        ab[oc * 2 + 1] = beta[oc] - mu * a;
    }
}

// ============ K4: BN+ReLU+pool from conv_out + final 1x1 (vectorized) ============
__global__ __launch_bounds__(512) void k_pool_reload(
    const __bf16* __restrict__ conv_out, const float* __restrict__ ab,
    const float* __restrict__ w2, const float* __restrict__ b2, float* __restrict__ out) {
    __shared__ float red[64][65];
    __shared__ float pooled[64], red2[2][64];
    int img = blockIdx.x, t = threadIdx.x;
    int pidx = t >> 3, ocg = t & 7;
    float a[8], bb[8];
#pragma unroll
    for (int j = 0; j < 8; ++j) {
        a[j]  = ab[(ocg * 8 + j) * 2];
        bb[j] = ab[(ocg * 8 + j) * 2 + 1];
    }
    float s[8];
#pragma unroll
    for (int j = 0; j < 8; ++j) s[j] = 0.f;
    const __bf16* src = conv_out + (size_t)img * Pp * 64 + ocg * 8;
    for (int p = pidx; p < Pp; p += 64) {
        short8 v = *(const short8*)(src + (size_t)p * 64);
#pragma unroll
        for (int j = 0; j < 8; ++j)
            s[j] += fmaxf(fmaf(a[j], tof(v[j]), bb[j]), 0.f);
    }
#pragma unroll
    for (int j = 0; j < 8; ++j) red[pidx][ocg * 8 + j] = s[j];
    __syncthreads();
    if (t < 64) {
        float S = 0.f;
        for (int p = 0; p < 64; ++p) S += red[p][t];
        pooled[t] = S * (1.f / (float)Pp);
    }
    __syncthreads();
    if (t < 128) {
        int j = t >> 6, c = t & 63;
        red2[j][c] = pooled[c] * w2[j * 64 + c];
    }
    __syncthreads();
    if (t < 2) {
        float ss = b2[t];
        for (int c = 0; c < 64; ++c) ss += red2[t][c];
        out[img * 2 + t] = ss;
    }
}

// ============ host ============
extern "C" void kernel_launch(void* const* d_in, const int* in_sizes, int n_in,
                              void* d_out, int out_size, void* d_ws, size_t ws_size,
                              hipStream_t stream) {
    const float* q   = (const float*)d_in[0];
    const float* hm  = (const float*)d_in[1];
    const float* w1  = (const float*)d_in[2];
    const float* b1  = (const float*)d_in[3];
    const float* w2  = (const float*)d_in[4];
    const float* b2  = (const float*)d_in[5];
    const float* w3  = (const float*)d_in[6];
    const float* b3  = (const float*)d_in[7];
    const float* cw  = (const float*)d_in[8];
    const float* cb  = (const float*)d_in[9];
    const float* gam = (const float*)d_in[10];
    const float* bet = (const float*)d_in[11];
    const float* c2w = (const float*)d_in[12];
    const float* c2b = (const float*)d_in[13];
    float* out = (float*)d_out;
    char* ws = (char*)d_ws;

    float* theta = (float*)(ws + OFF_THETA);
    __bf16* wb   = (__bf16*)(ws + OFF_WB);
    float* ab    = (float*)(ws + OFF_AB);

    bool hmt = ws_size >= NEED_HMT;
    __bf16* hmT      = (__bf16*)(ws + OFF_HMT);
    float* partials  = (float*)(ws + (hmt ? OFF_PART_H : OFF_PART_L));
    __bf16* conv_out = (__bf16*)(ws + (hmt ? OFF_CONV_H : OFF_CONV_L));

    k_prep<<<1016, 256, 0, stream>>>(q, w1, b1, w2, b2, w3, b3, cw, hm, theta, wb, hmT);
    if (hmt) {
        k_conv2<1><<<NBLK2, 512, 0, stream>>>(hm, hmT, theta, wb, cb, partials, conv_out);
    } else {
        k_conv2<0><<<NBLK2, 512, 0, stream>>>(hm, hmT, theta, wb, cb, partials, conv_out);
    }
    k_stats<<<64, 256, 0, stream>>>(partials, gam, bet, ab);
    k_pool_reload<<<NIMG, 512, 0, stream>>>(conv_out, ab, c2w, c2b, out);
}

// Round 13
// 116.151 us; speedup vs baseline: 1.2955x; 1.2955x over previous
//
#include <hip/hip_runtime.h>

// ---------------- problem constants ----------------
constexpr int Bc = 2, Nc = 256, CHM = 62;
constexpr int HW = 180;            // heatmap H=W
constexpr int OH = 38;             // conv out H=W
constexpr int Pp = OH * OH;        // 1444 positions
constexpr int NIMG = Bc * Nc;      // 512 images (n-major: img = n*B + b)
constexpr int R2 = 8;              // output rows per conv block
constexpr int NRB2 = 5;            // row-blocks per image (8,8,8,8,6)
constexpr int NBLK2 = NIMG * NRB2; // 2560
constexpr int KP = 576;            // padded K = 9 taps * 64 ch

// ---------------- ws layout (bytes) ----------------
constexpr size_t OFF_THETA = 0;            // 512*6*4        = 12,288
constexpr size_t OFF_WB    = 16384;        // 4*18*64*8 bf16 = 73,728 (fragment-ordered)
constexpr size_t OFF_AB    = 90112;        // 64*2*4         = 512
// hmT path:
constexpr size_t OFF_HMT    = 131072;      // 2*180*180*64*2 = 8,294,400 -> 8,425,472
constexpr size_t OFF_PART_H = 8425472;     // 2560*64*2*4    = 1,310,720 -> 9,736,192
constexpr size_t OFF_CONV_H = 9736192;     // + 94,633,984   -> 104,370,176
constexpr size_t NEED_HMT   = 104370176;   // proven available (rounds 4-12 ran this path)
// legacy path (no hmT):
constexpr size_t OFF_PART_L = 131072;
constexpr size_t OFF_CONV_L = 1441792;     // + 94,633,984 -> 96,075,776

typedef __attribute__((ext_vector_type(8))) short  short8;
typedef __attribute__((ext_vector_type(8))) __bf16 bf16x8;
typedef __attribute__((ext_vector_type(4))) float  f32x4;
typedef __attribute__((ext_vector_type(2))) float  f32x2;

__device__ __forceinline__ bf16x8 bc(short8 v) { return __builtin_bit_cast(bf16x8, v); }
__device__ __forceinline__ float tof(short s) {
    return __uint_as_float(((unsigned)(unsigned short)s) << 16);
}
__device__ __forceinline__ f32x2 up2(unsigned u) {
    f32x2 r;
    r.x = __uint_as_float(u << 16);
    r.y = __uint_as_float(u & 0xffff0000u);
    return r;
}

// ============ K1 (merged): theta MLP | weight cvt (fragment order) | hm transpose ============
// blocks [0,512): theta; [512,530): wcvt; [530,890): hmT
__global__ __launch_bounds__(256) void k_prep(
    const float* __restrict__ q,
    const float* __restrict__ w1, const float* __restrict__ b1,
    const float* __restrict__ w2, const float* __restrict__ b2,
    const float* __restrict__ w3, const float* __restrict__ b3,
    const float* __restrict__ cw, const float* __restrict__ hm,
    float* __restrict__ theta, __bf16* __restrict__ wb, __bf16* __restrict__ hmT) {
    int bid = blockIdx.x, t = threadIdx.x;
    if (bid < 512) {
        __shared__ float qv[256], h1[64], h2[64];
        int qi = bid;              // = b*N + n
        int b = qi >> 8, n = qi & 255;
        qv[t] = q[qi * 256 + t];
        __syncthreads();
        if (t < 64) {
            float s = b1[t];
            const float* wr = w1 + t * 256;
            for (int i = 0; i < 256; ++i) s = fmaf(qv[i], wr[i], s);
            h1[t] = fmaxf(s, 0.f);
        }
        __syncthreads();
        if (t < 64) {
            float s = b2[t];
            const float* wr = w2 + t * 64;
            for (int i = 0; i < 64; ++i) s = fmaf(h1[i], wr[i], s);
            h2[t] = fmaxf(s, 0.f);
        }
        __syncthreads();
        if (t < 6) {
            float s = b3[t];
            const float* wr = w3 + t * 64;
            for (int i = 0; i < 64; ++i) s = fmaf(h2[i], wr[i], s);
            theta[(n * Bc + b) * 6 + t] = s;
        }
    } else if (bid < 530) {
        // fragment-ordered B: wbf[(h*18+s)*64 + lane] = 8 bf16; lane=(col,chunk):
        // oc = h*16+col, k = s*32 + chunk*8 + j, k=(tap*64+ic)
        int idx16 = (bid - 512) * 256 + t;         // over 4*18*64 = 4608 exactly
        int lane = idx16 & 63;
        int hs = idx16 >> 6;                       // h*18 + s
        int h = hs / 18, s = hs - h * 18;
        int col = lane & 15, chunk = lane >> 4;
        int oc = h * 16 + col;
        int kb = s * 32 + chunk * 8;
        bf16x8 v;
#pragma unroll
        for (int j = 0; j < 8; ++j) {
            int k = kb + j;
            int tap = k >> 6, ic = k & 63;
            v[j] = (ic < CHM) ? (__bf16)cw[(oc * CHM + ic) * 9 + tap] : (__bf16)0.f;
        }
        *(bf16x8*)(wb + (size_t)idx16 * 8) = v;
    } else {
        int by = bid - 530;                        // b*180 + y
        int b = by / HW, y = by - b * HW;
        int x = t;
        if (x < HW) {
            const float* src = hm + (size_t)b * CHM * (HW * HW) + y * HW + x;
            __bf16* dst = hmT + ((size_t)(b * (HW * HW) + y * HW + x)) * 64;
#pragma unroll
            for (int g = 0; g < 8; ++g) {
                bf16x8 v;
#pragma unroll
                for (int j = 0; j < 8; ++j) {
                    int c = g * 8 + j;
                    v[j] = (c < CHM) ? (__bf16)src[(size_t)c * (HW * HW)] : (__bf16)0.f;
                }
                *(bf16x8*)(dst + g * 8) = v;
            }
        }
    }
}

// ============ K3: fused sample + MFMA implicit-GEMM conv (r11 structure) ============
// 512 threads = 8 waves = 4 oc-tiles (h) x 2 row-pair-parity (qp).
// strip LDS: [rx<=10*40][ic:64] bf16, 16B-granular swizzle: elem ^= (x&7)<<3
// sampling (HMT): task = (position, 8ch-group); 8 consecutive lanes share one
// 128B corner vector; f32x2 pk-fma blend.
// m-loop: s OUTER; B from fragment-ordered wbf -> per-s wave-load is a
// CONTIGUOUS 1KB (lane i at base + i*16B) instead of 16 scattered segments.
#define PREP(S, PIDX, VLD) \
    int o00##S, o10##S, o01##S, o11##S, eb##S, sw##S; \
    float w00##S, w10##S, w01##S, w11##S; \
    { int _p = (PIDX); \
      int _r = _p / 40, _x = _p - _r * 40; \
      float _gx = (2 * _x + 1) * 0.025f - 1.f; \
      float _gy = (2 * (oy0 + _r) + 1) * 0.025f - 1.f; \
      float _X = fmaf(t00, _gx, fmaf(t01, _gy, t02)); \
      float _Y = fmaf(t10, _gx, fmaf(t11, _gy, t12)); \
      float _ix = fmaf(_X, 90.f, 89.5f), _iy = fmaf(_Y, 90.f, 89.5f); \
      float _xf = floorf(_ix), _yf = floorf(_iy); \
      float _fx = _ix - _xf, _fy = _iy - _yf; \
      int _x0 = (int)_xf, _y0 = (int)_yf; \
      bool _xi0 = (unsigned)_x0 < (unsigned)HW, _xi1 = (unsigned)(_x0 + 1) < (unsigned)HW; \
      bool _yi0 = (unsigned)_y0 < (unsigned)HW, _yi1 = (unsigned)(_y0 + 1) < (unsigned)HW; \
      float _vm = (VLD) ? 1.f : 0.f; \
      w00##S = (_xi0 & _yi0) ? (1.f - _fx) * (1.f - _fy) * _vm : 0.f; \
      w10##S = (_xi1 & _yi0) ? _fx * (1.f - _fy) * _vm : 0.f; \
      w01##S = (_xi0 & _yi1) ? (1.f - _fx) * _fy * _vm : 0.f; \
      w11##S = (_xi1 & _yi1) ? _fx * _fy * _vm : 0.f; \
      o00##S = (_xi0 & _yi0) ? _y0 * HW + _x0 : 0; \
      o10##S = (_xi1 & _yi0) ? _y0 * HW + _x0 + 1 : 0; \
      o01##S = (_xi0 & _yi1) ? (_y0 + 1) * HW + _x0 : 0; \
      o11##S = (_xi1 & _yi1) ? (_y0 + 1) * HW + _x0 + 1 : 0; \
      eb##S = _p << 6; sw##S = (_x & 7) << 3; \
    }

template<int HMT>
__global__ __launch_bounds__(512, 4) void k_conv2(
    const float* __restrict__ heatmap, const __bf16* __restrict__ hmT,
    const float* __restrict__ theta, const __bf16* __restrict__ wb,
    const float* __restrict__ bias, float* __restrict__ partials,
    __bf16* __restrict__ conv_out) {
    __shared__ char smem[52224];                 // 51200 strip + 1KB red

    int bid = blockIdx.x;
    int n = bid & 255, bsel = (bid >> 8) & 1, ry = bid >> 9;
    int img = n * Bc + bsel;
    int oy0 = ry * R2;
    int nr  = (ry == NRB2 - 1) ? 6 : 8;          // output rows this block
    int t = threadIdx.x;
    int lane = t & 63, wv = t >> 6;
    int col = lane & 15, chunk = lane >> 4;
    int h = wv & 3, qp = wv >> 2;                // oc-tile, row-pair parity

    // ---- sampling ----
    const float* th = theta + img * 6;
    float t00 = th[0], t01 = th[1], t02 = th[2];
    float t10 = th[3], t11 = th[4], t12 = th[5];
    int rows = nr + 2, npos = rows * 40;

    if constexpr (HMT) {
        const char* hb = (const char*)(hmT + (size_t)bsel * ((size_t)HW * HW * 64));
        int ntask = npos * 8;                    // (position, ch-group) tasks
        for (int v = t; v < ntask; v += 512) {
            int p = v >> 3, cg = v & 7;
            PREP(T, p, true)
            int co = cg * 16;                    // byte offset of 8-ch group
            uint4 d00 = *(const uint4*)(hb + (size_t)o00T * 128 + co);
            uint4 d10 = *(const uint4*)(hb + (size_t)o10T * 128 + co);
            uint4 d01 = *(const uint4*)(hb + (size_t)o01T * 128 + co);
            uint4 d11 = *(const uint4*)(hb + (size_t)o11T * 128 + co);
            f32x2 W00 = {w00T, w00T}, W10 = {w10T, w10T};
            f32x2 W01 = {w01T, w01T}, W11 = {w11T, w11T};
            bf16x8 v0;
#pragma unroll
            for (int j = 0; j < 4; ++j) {
                f32x2 r = up2((&d11.x)[j]) * W11;
                r = __builtin_elementwise_fma(up2((&d01.x)[j]), W01, r);
                r = __builtin_elementwise_fma(up2((&d10.x)[j]), W10, r);
                r = __builtin_elementwise_fma(up2((&d00.x)[j]), W00, r);
                v0[2 * j]     = (__bf16)r.x;
                v0[2 * j + 1] = (__bf16)r.y;
            }
            *(bf16x8*)(smem + 2 * (ebT | ((cg * 8) ^ swT))) = v0;
        }
    } else {
        if (t < npos) {
            PREP(A, t, true)
            char* sb0 = smem + 2 * ebA;
            const float* hmb = heatmap + (size_t)bsel * CHM * HW * HW;
            auto dofetch = [&](int c) -> float {
                const float* pl = hmb + c * (HW * HW);
                return fmaf(w00A, pl[o00A], fmaf(w10A, pl[o10A],
                       fmaf(w01A, pl[o01A], w11A * pl[o11A])));
            };
#pragma unroll
            for (int cg = 0; cg < 8; ++cg) {
                bf16x8 v0;
#pragma unroll
                for (int j = 0; j < 8; ++j) {
                    int c = cg * 8 + j;
                    v0[j] = (c < CHM) ? (__bf16)dofetch(c) : (__bf16)0.f;
                }
                *(bf16x8*)(sb0 + 2 * ((cg * 8) ^ swA)) = v0;
            }
        }
    }
    __syncthreads();

    // ---- MFMA m-loop: s OUTER; tiles = 2 row-pairs x 5 x-tiles per wave ----
    // wave qp handles row-pairs oyp0 = 2*qp and oyp1 = 2*qp+4.
    // lane m=col -> (x = xb*8 + (col&7), row = oyp + (col>>3)).
    float bia = bias[h * 16 + col];
    float ssum = 0.f, ssq = 0.f;
    int cl = col & 7;
    int ch8 = (col >> 3) * 5120;
    int cb = chunk << 4;
    int oyp0 = qp * 2, oyp1 = qp * 2 + 4;
    bool has2 = (oyp1 + 1) < nr;                 // second row-pair valid
    // fragment-ordered B: contiguous 1KB per (h,s), lane offset = lane*16
    const char* wp = (const char*)wb + ((size_t)(h * 18) * 64 + lane) * 16;
    int base0 = oyp0 * 5120, base1 = oyp1 * 5120;

    f32x4 accA[5], accB[5];
#pragma unroll
    for (int xb = 0; xb < 5; ++xb) {
        accA[xb] = f32x4{0.f, 0.f, 0.f, 0.f};
        accB[xb] = f32x4{0.f, 0.f, 0.f, 0.f};
    }

    __builtin_amdgcn_s_setprio(1);
#pragma unroll
    for (int s = 0; s < 18; ++s) {
        const int tap = s >> 1;
        const int ky = tap / 3, kx = tap % 3;
        const int hb2 = (s & 1) << 6;
        short8 bs = *(const short8*)(wp + s * 1024);    // coalesced 1KB B fragment
        int t1 = cl + kx;
        int loff = ch8 + ky * 5120 + t1 * 128 + ((hb2 | cb) ^ ((t1 & 7) << 4));
        const char* p0 = smem + base0 + loff;
        const char* p1 = smem + base1 + loff;
#pragma unroll
        for (int xb = 0; xb < 5; ++xb) {
            short8 a0 = *(const short8*)(p0 + xb * 1024);
            accA[xb] = __builtin_amdgcn_mfma_f32_16x16x32_bf16(bc(a0), bc(bs), accA[xb], 0, 0, 0);
        }
        if (has2) {
#pragma unroll
            for (int xb = 0; xb < 5; ++xb) {
                short8 a1 = *(const short8*)(p1 + xb * 1024);
                accB[xb] = __builtin_amdgcn_mfma_f32_16x16x32_bf16(bc(a1), bc(bs), accB[xb], 0, 0, 0);
            }
        }
    }
    __builtin_amdgcn_s_setprio(0);

    // epilogue: C row m = chunk*4+r2 -> x = xb*8 + (m&7), row = oyp + (m>>3)
    __bf16* cobase = conv_out + ((size_t)img * Pp + oy0 * 38) * 64 + (h * 16 + col);
    auto epi = [&](f32x4 (&ac)[5], int oyp) {
#pragma unroll
        for (int xb = 0; xb < 5; ++xb) {
#pragma unroll
            for (int r2 = 0; r2 < 4; ++r2) {
                int m = chunk * 4 + r2;
                int x = xb * 8 + (m & 7);
                if (x < 38) {
                    int row = oyp + (m >> 3);
                    float v = ac[xb][r2] + bia;
                    cobase[(size_t)(row * 38 + x) * 64] = (__bf16)v;
                    ssum += v; ssq = fmaf(v, v, ssq);
                }
            }
        }
    };
    epi(accA, oyp0);
    if (has2) epi(accB, oyp1);

    // cross-lane: sum lanes {l, l^16, l^32, l^48} (same oc col)
    ssum += __shfl_xor(ssum, 16); ssum += __shfl_xor(ssum, 32);
    ssq  += __shfl_xor(ssq, 16);  ssq  += __shfl_xor(ssq, 32);

    // combine the two qp-waves via LDS red region [2][64][2] @ 51200
    float* redq = (float*)(smem + 51200);
    if (lane < 16) {
        int o = (qp * 64 + h * 16 + lane) * 2;
        redq[o] = ssum; redq[o + 1] = ssq;
    }
    __syncthreads();
    if (t < 64) {
        float S  = redq[t * 2]     + redq[(64 + t) * 2];
        float S2 = redq[t * 2 + 1] + redq[(64 + t) * 2 + 1];
        partials[((size_t)bid * 64 + t) * 2]     = S;
        partials[((size_t)bid * 64 + t) * 2 + 1] = S2;
    }
}

// ============ K3b: reduce per-block sums -> BN a,b per channel ============
__global__ void k_stats(const float* __restrict__ partials, const float* __restrict__ gamma,
                        const float* __restrict__ beta, float* __restrict__ ab) {
    __shared__ float red[256][2];
    int oc = blockIdx.x, t = threadIdx.x;
    float S = 0.f, S2 = 0.f;
    for (int j = t; j < NBLK2; j += 256) {
        S  += partials[((size_t)j * 64 + oc) * 2];
        S2 += partials[((size_t)j * 64 + oc) * 2 + 1];
    }
    red[t][0] = S; red[t][1] = S2;
    __syncthreads();
    for (int off = 128; off >= 1; off >>= 1) {
        if (t < off) { red[t][0] += red[t + off][0]; red[t][1] += red[t + off][1]; }
        __syncthreads();
    }
    if (t == 0) {
        float cnt = (float)NIMG * (float)Pp;
        float mu  = red[0][0] / cnt;
        float var = red[0][1] / cnt - mu * mu;
        float a = gamma[oc] * rsqrtf(var + 1e-5f);
        ab[oc * 2] = a;
        ab[oc * 2 + 1] = beta[oc] - mu * a;
    }
}

// ============ K4: BN+ReLU+pool from conv_out + final 1x1 (vectorized) ============
__global__ __launch_bounds__(512) void k_pool_reload(
    const __bf16* __restrict__ conv_out, const float* __restrict__ ab,
    const float* __restrict__ w2, const float* __restrict__ b2, float* __restrict__ out) {
    __shared__ float red[64][65];
    __shared__ float pooled[64], red2[2][64];
    int img = blockIdx.x, t = threadIdx.x;
    int pidx = t >> 3, ocg = t & 7;
    float a[8], bb[8];
#pragma unroll
    for (int j = 0; j < 8; ++j) {
        a[j]  = ab[(ocg * 8 + j) * 2];
        bb[j] = ab[(ocg * 8 + j) * 2 + 1];
    }
    float s[8];
#pragma unroll
    for (int j = 0; j < 8; ++j) s[j] = 0.f;
    const __bf16* src = conv_out + (size_t)img * Pp * 64 + ocg * 8;
    for (int p = pidx; p < Pp; p += 64) {
        short8 v = *(const short8*)(src + (size_t)p * 64);
#pragma unroll
        for (int j = 0; j < 8; ++j)
            s[j] += fmaxf(fmaf(a[j], tof(v[j]), bb[j]), 0.f);
    }
#pragma unroll
    for (int j = 0; j < 8; ++j) red[pidx][ocg * 8 + j] = s[j];
    __syncthreads();
    if (t < 64) {
        float S = 0.f;
        for (int p = 0; p < 64; ++p) S += red[p][t];
        pooled[t] = S * (1.f / (float)Pp);
    }
    __syncthreads();
    if (t < 128) {
        int j = t >> 6, c = t & 63;
        red2[j][c] = pooled[c] * w2[j * 64 + c];
    }
    __syncthreads();
    if (t < 2) {
        float ss = b2[t];
        for (int c = 0; c < 64; ++c) ss += red2[t][c];
        out[img * 2 + t] = ss;
    }
}

// ============ host ============
extern "C" void kernel_launch(void* const* d_in, const int* in_sizes, int n_in,
                              void* d_out, int out_size, void* d_ws, size_t ws_size,
                              hipStream_t stream) {
    const float* q   = (const float*)d_in[0];
    const float* hm  = (const float*)d_in[1];
    const float* w1  = (const float*)d_in[2];
    const float* b1  = (const float*)d_in[3];
    const float* w2  = (const float*)d_in[4];
    const float* b2  = (const float*)d_in[5];
    const float* w3  = (const float*)d_in[6];
    const float* b3  = (const float*)d_in[7];
    const float* cw  = (const float*)d_in[8];
    const float* cb  = (const float*)d_in[9];
    const float* gam = (const float*)d_in[10];
    const float* bet = (const float*)d_in[11];
    const float* c2w = (const float*)d_in[12];
    const float* c2b = (const float*)d_in[13];
    float* out = (float*)d_out;
    char* ws = (char*)d_ws;

    float* theta = (float*)(ws + OFF_THETA);
    __bf16* wb   = (__bf16*)(ws + OFF_WB);
    float* ab    = (float*)(ws + OFF_AB);

    bool hmt = ws_size >= NEED_HMT;
    __bf16* hmT      = (__bf16*)(ws + OFF_HMT);
    float* partials  = (float*)(ws + (hmt ? OFF_PART_H : OFF_PART_L));
    __bf16* conv_out = (__bf16*)(ws + (hmt ? OFF_CONV_H : OFF_CONV_L));

    k_prep<<<890, 256, 0, stream>>>(q, w1, b1, w2, b2, w3, b3, cw, hm, theta, wb, hmT);
    if (hmt) {
        k_conv2<1><<<NBLK2, 512, 0, stream>>>(hm, hmT, theta, wb, cb, partials, conv_out);
    } else {
        k_conv2<0><<<NBLK2, 512, 0, stream>>>(hm, hmT, theta, wb, cb, partials, conv_out);
    }
    k_stats<<<64, 256, 0, stream>>>(partials, gam, bet, ab);
    k_pool_reload<<<NIMG, 512, 0, stream>>>(conv_out, ab, c2w, c2b, out);
}

// Round 14
// 115.266 us; speedup vs baseline: 1.3054x; 1.0077x over previous
//
#include <hip/hip_runtime.h>

// ---------------- problem constants ----------------
constexpr int Bc = 2, Nc = 256, CHM = 62;
constexpr int HW = 180;            // heatmap H=W
constexpr int OH = 38;             // conv out H=W
constexpr int Pp = OH * OH;        // 1444 positions
constexpr int NIMG = Bc * Nc;      // 512 images (n-major: img = n*B + b)
constexpr int R2 = 8;              // output rows per conv block
constexpr int NRB2 = 5;            // row-blocks per image (8,8,8,8,6)
constexpr int NBLK2 = NIMG * NRB2; // 2560
constexpr int KP = 576;            // padded K = 9 taps * 64 ch

// ---------------- ws layout (bytes) ----------------
constexpr size_t OFF_THETA = 0;            // 512*6*4        = 12,288
constexpr size_t OFF_WB    = 16384;        // 4*18*64*8 bf16 = 73,728 (fragment-ordered)
constexpr size_t OFF_AB    = 90112;        // 64*2*4         = 512
// hmT path:
constexpr size_t OFF_HMT    = 131072;      // 2*180*180*64*2 = 8,294,400 -> 8,425,472
constexpr size_t OFF_PART_H = 8425472;     // 2560*64*2*4    = 1,310,720 -> 9,736,192
constexpr size_t OFF_CONV_H = 9736192;     // + 94,633,984   -> 104,370,176
constexpr size_t NEED_HMT   = 104370176;   // proven available (rounds 4-13 ran this path)
// legacy path (no hmT):
constexpr size_t OFF_PART_L = 131072;
constexpr size_t OFF_CONV_L = 1441792;     // + 94,633,984 -> 96,075,776

typedef __attribute__((ext_vector_type(8))) short  short8;
typedef __attribute__((ext_vector_type(8))) __bf16 bf16x8;
typedef __attribute__((ext_vector_type(4))) float  f32x4;
typedef __attribute__((ext_vector_type(2))) float  f32x2;

__device__ __forceinline__ bf16x8 bc(short8 v) { return __builtin_bit_cast(bf16x8, v); }
__device__ __forceinline__ float tof(short s) {
    return __uint_as_float(((unsigned)(unsigned short)s) << 16);
}
__device__ __forceinline__ f32x2 up2(unsigned u) {
    f32x2 r;
    r.x = __uint_as_float(u << 16);
    r.y = __uint_as_float(u & 0xffff0000u);
    return r;
}

// ============ K1 (merged): theta MLP | weight cvt (fragment order) | hm transpose ============
// blocks [0,512): theta; [512,530): wcvt; [530,890): hmT
__global__ __launch_bounds__(256) void k_prep(
    const float* __restrict__ q,
    const float* __restrict__ w1, const float* __restrict__ b1,
    const float* __restrict__ w2, const float* __restrict__ b2,
    const float* __restrict__ w3, const float* __restrict__ b3,
    const float* __restrict__ cw, const float* __restrict__ hm,
    float* __restrict__ theta, __bf16* __restrict__ wb, __bf16* __restrict__ hmT) {
    int bid = blockIdx.x, t = threadIdx.x;
    if (bid < 512) {
        __shared__ float qv[256], h1[64], h2[64];
        int qi = bid;              // = b*N + n
        int b = qi >> 8, n = qi & 255;
        qv[t] = q[qi * 256 + t];
        __syncthreads();
        if (t < 64) {
            float s = b1[t];
            const float* wr = w1 + t * 256;
            for (int i = 0; i < 256; ++i) s = fmaf(qv[i], wr[i], s);
            h1[t] = fmaxf(s, 0.f);
        }
        __syncthreads();
        if (t < 64) {
            float s = b2[t];
            const float* wr = w2 + t * 64;
            for (int i = 0; i < 64; ++i) s = fmaf(h1[i], wr[i], s);
            h2[t] = fmaxf(s, 0.f);
        }
        __syncthreads();
        if (t < 6) {
            float s = b3[t];
            const float* wr = w3 + t * 64;
            for (int i = 0; i < 64; ++i) s = fmaf(h2[i], wr[i], s);
            theta[(n * Bc + b) * 6 + t] = s;
        }
    } else if (bid < 530) {
        // fragment-ordered B: wbf[(h*18+s)*64 + lane] = 8 bf16; lane=(col,chunk):
        // oc = h*16+col, k = s*32 + chunk*8 + j, k=(tap*64+ic)
        int idx16 = (bid - 512) * 256 + t;         // over 4*18*64 = 4608 exactly
        int lane = idx16 & 63;
        int hs = idx16 >> 6;                       // h*18 + s
        int h = hs / 18, s = hs - h * 18;
        int col = lane & 15, chunk = lane >> 4;
        int oc = h * 16 + col;
        int kb = s * 32 + chunk * 8;
        bf16x8 v;
#pragma unroll
        for (int j = 0; j < 8; ++j) {
            int k = kb + j;
            int tap = k >> 6, ic = k & 63;
            v[j] = (ic < CHM) ? (__bf16)cw[(oc * CHM + ic) * 9 + tap] : (__bf16)0.f;
        }
        *(bf16x8*)(wb + (size_t)idx16 * 8) = v;
    } else {
        int by = bid - 530;                        // b*180 + y
        int b = by / HW, y = by - b * HW;
        int x = t;
        if (x < HW) {
            const float* src = hm + (size_t)b * CHM * (HW * HW) + y * HW + x;
            __bf16* dst = hmT + ((size_t)(b * (HW * HW) + y * HW + x)) * 64;
#pragma unroll
            for (int g = 0; g < 8; ++g) {
                bf16x8 v;
#pragma unroll
                for (int j = 0; j < 8; ++j) {
                    int c = g * 8 + j;
                    v[j] = (c < CHM) ? (__bf16)src[(size_t)c * (HW * HW)] : (__bf16)0.f;
                }
                *(bf16x8*)(dst + g * 8) = v;
            }
        }
    }
}

// ============ K3: fused sample + MFMA implicit-GEMM conv ============
// 512 threads = 8 waves = 2 oc-halves (hg, 32 oc) x 4 row-pairs (qp).
// strip LDS: [rx<=10*40][ic:64] bf16, 16B-granular swizzle: elem ^= (x&7)<<3
// sampling (HMT): task = (position, 8ch-group); 8 consecutive lanes share one
// 128B corner vector; f32x2 pk-fma blend.
// m-loop: s OUTER; one A ds_read feeds TWO MFMAs (2 n-tiles/wave) -> A-read
// LDS traffic halved vs r13; B-fragments are CONTIGUOUS 1KB wave-loads
// (fragment-ordered wb) -- the confound that sank r12 is removed.
#define PREP(S, PIDX, VLD) \
    int o00##S, o10##S, o01##S, o11##S, eb##S, sw##S; \
    float w00##S, w10##S, w01##S, w11##S; \
    { int _p = (PIDX); \
      int _r = _p / 40, _x = _p - _r * 40; \
      float _gx = (2 * _x + 1) * 0.025f - 1.f; \
      float _gy = (2 * (oy0 + _r) + 1) * 0.025f - 1.f; \
      float _X = fmaf(t00, _gx, fmaf(t01, _gy, t02)); \
      float _Y = fmaf(t10, _gx, fmaf(t11, _gy, t12)); \
      float _ix = fmaf(_X, 90.f, 89.5f), _iy = fmaf(_Y, 90.f, 89.5f); \
      float _xf = floorf(_ix), _yf = floorf(_iy); \
      float _fx = _ix - _xf, _fy = _iy - _yf; \
      int _x0 = (int)_xf, _y0 = (int)_yf; \
      bool _xi0 = (unsigned)_x0 < (unsigned)HW, _xi1 = (unsigned)(_x0 + 1) < (unsigned)HW; \
      bool _yi0 = (unsigned)_y0 < (unsigned)HW, _yi1 = (unsigned)(_y0 + 1) < (unsigned)HW; \
      float _vm = (VLD) ? 1.f : 0.f; \
      w00##S = (_xi0 & _yi0) ? (1.f - _fx) * (1.f - _fy) * _vm : 0.f; \
      w10##S = (_xi1 & _yi0) ? _fx * (1.f - _fy) * _vm : 0.f; \
      w01##S = (_xi0 & _yi1) ? (1.f - _fx) * _fy * _vm : 0.f; \
      w11##S = (_xi1 & _yi1) ? _fx * _fy * _vm : 0.f; \
      o00##S = (_xi0 & _yi0) ? _y0 * HW + _x0 : 0; \
      o10##S = (_xi1 & _yi0) ? _y0 * HW + _x0 + 1 : 0; \
      o01##S = (_xi0 & _yi1) ? (_y0 + 1) * HW + _x0 : 0; \
      o11##S = (_xi1 & _yi1) ? (_y0 + 1) * HW + _x0 + 1 : 0; \
      eb##S = _p << 6; sw##S = (_x & 7) << 3; \
    }

template<int HMT>
__global__ __launch_bounds__(512, 4) void k_conv2(
    const float* __restrict__ heatmap, const __bf16* __restrict__ hmT,
    const float* __restrict__ theta, const __bf16* __restrict__ wb,
    const float* __restrict__ bias, float* __restrict__ partials,
    __bf16* __restrict__ conv_out) {
    __shared__ char smem[53248];                 // 51200 strip + 2KB red

    int bid = blockIdx.x;
    int n = bid & 255, bsel = (bid >> 8) & 1, ry = bid >> 9;
    int img = n * Bc + bsel;
    int oy0 = ry * R2;
    int nr  = (ry == NRB2 - 1) ? 6 : 8;          // output rows this block
    int t = threadIdx.x;
    int lane = t & 63, wv = t >> 6;
    int col = lane & 15, chunk = lane >> 4;
    int hg = wv & 1, qp = wv >> 1;               // oc-half, row-pair

    // ---- sampling ----
    const float* th = theta + img * 6;
    float t00 = th[0], t01 = th[1], t02 = th[2];
    float t10 = th[3], t11 = th[4], t12 = th[5];
    int rows = nr + 2, npos = rows * 40;

    if constexpr (HMT) {
        const char* hb = (const char*)(hmT + (size_t)bsel * ((size_t)HW * HW * 64));
        int ntask = npos * 8;                    // (position, ch-group) tasks
        for (int v = t; v < ntask; v += 512) {
            int p = v >> 3, cg = v & 7;
            PREP(T, p, true)
            int co = cg * 16;                    // byte offset of 8-ch group
            uint4 d00 = *(const uint4*)(hb + (size_t)o00T * 128 + co);
            uint4 d10 = *(const uint4*)(hb + (size_t)o10T * 128 + co);
            uint4 d01 = *(const uint4*)(hb + (size_t)o01T * 128 + co);
            uint4 d11 = *(const uint4*)(hb + (size_t)o11T * 128 + co);
            f32x2 W00 = {w00T, w00T}, W10 = {w10T, w10T};
            f32x2 W01 = {w01T, w01T}, W11 = {w11T, w11T};
            bf16x8 v0;
#pragma unroll
            for (int j = 0; j < 4; ++j) {
                f32x2 r = up2((&d11.x)[j]) * W11;
                r = __builtin_elementwise_fma(up2((&d01.x)[j]), W01, r);
                r = __builtin_elementwise_fma(up2((&d10.x)[j]), W10, r);
                r = __builtin_elementwise_fma(up2((&d00.x)[j]), W00, r);
                v0[2 * j]     = (__bf16)r.x;
                v0[2 * j + 1] = (__bf16)r.y;
            }
            *(bf16x8*)(smem + 2 * (ebT | ((cg * 8) ^ swT))) = v0;
        }
    } else {
        if (t < npos) {
            PREP(A, t, true)
            char* sb0 = smem + 2 * ebA;
            const float* hmb = heatmap + (size_t)bsel * CHM * HW * HW;
            auto dofetch = [&](int c) -> float {
                const float* pl = hmb + c * (HW * HW);
                return fmaf(w00A, pl[o00A], fmaf(w10A, pl[o10A],
                       fmaf(w01A, pl[o01A], w11A * pl[o11A])));
            };
#pragma unroll
            for (int cg = 0; cg < 8; ++cg) {
                bf16x8 v0;
#pragma unroll
                for (int j = 0; j < 8; ++j) {
                    int c = cg * 8 + j;
                    v0[j] = (c < CHM) ? (__bf16)dofetch(c) : (__bf16)0.f;
                }
                *(bf16x8*)(sb0 + 2 * ((cg * 8) ^ swA)) = v0;
            }
        }
    }
    __syncthreads();

    // ---- MFMA m-loop: s OUTER; wave (hg,qp) -> 32 oc (2 n-tiles), 1 row-pair ----
    // lane m=col -> (x = xb*8 + (col&7), row = oyp + (col>>3)).
    float bia0 = bias[hg * 32 + col], bia1 = bias[hg * 32 + 16 + col];
    float ssum0 = 0.f, ssq0 = 0.f, ssum1 = 0.f, ssq1 = 0.f;
    int cl = col & 7;
    int ch8 = (col >> 3) * 5120;
    int cb = chunk << 4;
    int oyp = qp * 2;
    bool valid = (oyp + 1) < nr;                 // qp=3 idle when nr=6
    // fragment-ordered B: contiguous 1KB per (h,s); h0 = hg*2, h1 = hg*2+1
    const char* wp0 = (const char*)wb + ((size_t)(hg * 2 * 18) * 64 + lane) * 16;
    const char* wp1 = wp0 + (size_t)18 * 64 * 16;   // +18432
    int base0 = oyp * 5120;

    f32x4 accP[5], accQ[5];
#pragma unroll
    for (int xb = 0; xb < 5; ++xb) {
        accP[xb] = f32x4{0.f, 0.f, 0.f, 0.f};
        accQ[xb] = f32x4{0.f, 0.f, 0.f, 0.f};
    }

    if (valid) {
        __builtin_amdgcn_s_setprio(1);
#pragma unroll
        for (int s = 0; s < 18; ++s) {
            const int tap = s >> 1;
            const int ky = tap / 3, kx = tap % 3;
            const int hb2 = (s & 1) << 6;
            short8 bs0 = *(const short8*)(wp0 + s * 1024);  // coalesced 1KB B frags
            short8 bs1 = *(const short8*)(wp1 + s * 1024);
            int t1 = cl + kx;
            int loff = ch8 + ky * 5120 + t1 * 128 + ((hb2 | cb) ^ ((t1 & 7) << 4));
            const char* p0 = smem + base0 + loff;
#pragma unroll
            for (int xb = 0; xb < 5; ++xb) {
                short8 a0 = *(const short8*)(p0 + xb * 1024);
                accP[xb] = __builtin_amdgcn_mfma_f32_16x16x32_bf16(bc(a0), bc(bs0), accP[xb], 0, 0, 0);
                accQ[xb] = __builtin_amdgcn_mfma_f32_16x16x32_bf16(bc(a0), bc(bs1), accQ[xb], 0, 0, 0);
            }
        }
        __builtin_amdgcn_s_setprio(0);

        // epilogue: C row m = chunk*4+r2 -> x = xb*8 + (m&7), row = oyp + (m>>3)
        __bf16* cobase0 = conv_out + ((size_t)img * Pp + oy0 * 38) * 64 + (hg * 32 + col);
        __bf16* cobase1 = cobase0 + 16;
#pragma unroll
        for (int xb = 0; xb < 5; ++xb) {
#pragma unroll
            for (int r2 = 0; r2 < 4; ++r2) {
                int m = chunk * 4 + r2;
                int x = xb * 8 + (m & 7);
                if (x < 38) {
                    int row = oyp + (m >> 3);
                    size_t po = (size_t)(row * 38 + x) * 64;
                    float v0 = accP[xb][r2] + bia0;
                    cobase0[po] = (__bf16)v0;
                    ssum0 += v0; ssq0 = fmaf(v0, v0, ssq0);
                    float v1 = accQ[xb][r2] + bia1;
                    cobase1[po] = (__bf16)v1;
                    ssum1 += v1; ssq1 = fmaf(v1, v1, ssq1);
                }
            }
        }
    }

    // cross-lane: sum lanes {l, l^16, l^32, l^48} (same oc col)
    ssum0 += __shfl_xor(ssum0, 16); ssum0 += __shfl_xor(ssum0, 32);
    ssq0  += __shfl_xor(ssq0, 16);  ssq0  += __shfl_xor(ssq0, 32);
    ssum1 += __shfl_xor(ssum1, 16); ssum1 += __shfl_xor(ssum1, 32);
    ssq1  += __shfl_xor(ssq1, 16);  ssq1  += __shfl_xor(ssq1, 32);

    // combine 4 qp-waves via LDS red region [4][64][2] @ 51200
    float* redq = (float*)(smem + 51200);
    if (lane < 16) {
        int o = (qp * 64 + hg * 32 + lane) * 2;
        redq[o]      = ssum0; redq[o + 1]  = ssq0;
        redq[o + 32] = ssum1; redq[o + 33] = ssq1;   // +16 oc -> +32 floats
    }
    __syncthreads();
    if (t < 64) {
        float S = 0.f, S2 = 0.f;
#pragma unroll
        for (int g = 0; g < 4; ++g) {
            S  += redq[(g * 64 + t) * 2];
            S2 += redq[(g * 64 + t) * 2 + 1];
        }
        partials[((size_t)bid * 64 + t) * 2]     = S;
        partials[((size_t)bid * 64 + t) * 2 + 1] = S2;
    }
}

// ============ K3b: reduce per-block sums -> BN a,b per channel ============
__global__ void k_stats(const float* __restrict__ partials, const float* __restrict__ gamma,
                        const float* __restrict__ beta, float* __restrict__ ab) {
    __shared__ float red[256][2];
    int oc = blockIdx.x, t = threadIdx.x;
    float S = 0.f, S2 = 0.f;
    for (int j = t; j < NBLK2; j += 256) {
        S  += partials[((size_t)j * 64 + oc) * 2];
        S2 += partials[((size_t)j * 64 + oc) * 2 + 1];
    }
    red[t][0] = S; red[t][1] = S2;
    __syncthreads();
    for (int off = 128; off >= 1; off >>= 1) {
        if (t < off) { red[t][0] += red[t + off][0]; red[t][1] += red[t + off][1]; }
        __syncthreads();
    }
    if (t == 0) {
        float cnt = (float)NIMG * (float)Pp;
        float mu  = red[0][0] / cnt;
        float var = red[0][1] / cnt - mu * mu;
        float a = gamma[oc] * rsqrtf(var + 1e-5f);
        ab[oc * 2] = a;
        ab[oc * 2 + 1] = beta[oc] - mu * a;
    }
}

// ============ K4: BN+ReLU+pool from conv_out + final 1x1 (vectorized) ============
__global__ __launch_bounds__(512) void k_pool_reload(
    const __bf16* __restrict__ conv_out, const float* __restrict__ ab,
    const float* __restrict__ w2, const float* __restrict__ b2, float* __restrict__ out) {
    __shared__ float red[64][65];
    __shared__ float pooled[64], red2[2][64];
    int img = blockIdx.x, t = threadIdx.x;
    int pidx = t >> 3, ocg = t & 7;
    float a[8], bb[8];
#pragma unroll
    for (int j = 0; j < 8; ++j) {
        a[j]  = ab[(ocg * 8 + j) * 2];
        bb[j] = ab[(ocg * 8 + j) * 2 + 1];
    }
    float s[8];
#pragma unroll
    for (int j = 0; j < 8; ++j) s[j] = 0.f;
    const __bf16* src = conv_out + (size_t)img * Pp * 64 + ocg * 8;
    for (int p = pidx; p < Pp; p += 64) {
        short8 v = *(const short8*)(src + (size_t)p * 64);
#pragma unroll
        for (int j = 0; j < 8; ++j)
            s[j] += fmaxf(fmaf(a[j], tof(v[j]), bb[j]), 0.f);
    }
#pragma unroll
    for (int j = 0; j < 8; ++j) red[pidx][ocg * 8 + j] = s[j];
    __syncthreads();
    if (t < 64) {
        float S = 0.f;
        for (int p = 0; p < 64; ++p) S += red[p][t];
        pooled[t] = S * (1.f / (float)Pp);
    }
    __syncthreads();
    if (t < 128) {
        int j = t >> 6, c = t & 63;
        red2[j][c] = pooled[c] * w2[j * 64 + c];
    }
    __syncthreads();
    if (t < 2) {
        float ss = b2[t];
        for (int c = 0; c < 64; ++c) ss += red2[t][c];
        out[img * 2 + t] = ss;
    }
}

// ============ host ============
extern "C" void kernel_launch(void* const* d_in, const int* in_sizes, int n_in,
                              void* d_out, int out_size, void* d_ws, size_t ws_size,
                              hipStream_t stream) {
    const float* q   = (const float*)d_in[0];
    const float* hm  = (const float*)d_in[1];
    const float* w1  = (const float*)d_in[2];
    const float* b1  = (const float*)d_in[3];
    const float* w2  = (const float*)d_in[4];
    const float* b2  = (const float*)d_in[5];
    const float* w3  = (const float*)d_in[6];
    const float* b3  = (const float*)d_in[7];
    const float* cw  = (const float*)d_in[8];
    const float* cb  = (const float*)d_in[9];
    const float* gam = (const float*)d_in[10];
    const float* bet = (const float*)d_in[11];
    const float* c2w = (const float*)d_in[12];
    const float* c2b = (const float*)d_in[13];
    float* out = (float*)d_out;
    char* ws = (char*)d_ws;

    float* theta = (float*)(ws + OFF_THETA);
    __bf16* wb   = (__bf16*)(ws + OFF_WB);
    float* ab    = (float*)(ws + OFF_AB);

    bool hmt = ws_size >= NEED_HMT;
    __bf16* hmT      = (__bf16*)(ws + OFF_HMT);
    float* partials  = (float*)(ws + (hmt ? OFF_PART_H : OFF_PART_L));
    __bf16* conv_out = (__bf16*)(ws + (hmt ? OFF_CONV_H : OFF_CONV_L));

    k_prep<<<890, 256, 0, stream>>>(q, w1, b1, w2, b2, w3, b3, cw, hm, theta, wb, hmT);
    if (hmt) {
        k_conv2<1><<<NBLK2, 512, 0, stream>>>(hm, hmT, theta, wb, cb, partials, conv_out);
    } else {
        k_conv2<0><<<NBLK2, 512, 0, stream>>>(hm, hmT, theta, wb, cb, partials, conv_out);
    }
    k_stats<<<64, 256, 0, stream>>>(partials, gam, bet, ab);
    k_pool_reload<<<NIMG, 512, 0, stream>>>(conv_out, ab, c2w, c2b, out);
}